// Round 3
// baseline (276.684 us; speedup 1.0000x reference)
//
#include <hip/hip_runtime.h>
#include <hip/hip_bf16.h>

typedef __attribute__((ext_vector_type(8))) short bf16x8;
typedef __attribute__((ext_vector_type(4))) float f32x4;
typedef __attribute__((ext_vector_type(4))) unsigned short u16x4;
typedef __attribute__((ext_vector_type(8))) unsigned short u16x8;

#define M_DIM 4096
#define N_DIM 1024
#define IN_F  1024
#define K_DIM 12288   // IN_F * 12  (11 spline slots + 1 residual slot)
#define KS2   2
#define KPART2 (K_DIM / KS2)   // 6144
#define BK 64
#define NT (KPART2 / BK)       // 96

__device__ __forceinline__ unsigned short f2b(float v) {
  __hip_bfloat16 h = __float2bfloat16(v);
  return *reinterpret_cast<unsigned short*>(&h);
}

// Uniform cubic B-spline, grid = linspace(-1.75, 1.75, 15), h = 0.25.
__device__ __forceinline__ void spline12(float xv, float* w) {
  float t  = tanhf(xv);
  float tf = (t + 1.75f) * 4.0f;          // in (3,11) since t in (-1,1)
  int j = (int)tf;
  j = j < 3 ? 3 : (j > 10 ? 10 : j);
  float u  = tf - (float)j;
  float um = 1.0f - u;
  float u2 = u * u;
  float w0 = um * um * um * (1.0f / 6.0f);
  float w1 = (0.5f * u - 1.0f) * u2 + (2.0f / 3.0f);
  float w2 = ((-0.5f * u + 0.5f) * u + 0.5f) * u + (1.0f / 6.0f);
  float w3 = u * u2 * (1.0f / 6.0f);
  int base = j - 3;                        // in [0,7]
  #pragma unroll
  for (int s = 0; s < 11; ++s) {
    int r = s - base;
    w[s] = (r == 0) ? w0 : (r == 1) ? w1 : (r == 2) ? w2 : (r == 3) ? w3 : 0.0f;
  }
  w[11] = xv;
}

// ---------------- Pass 1b: A[b][i*12+n] bf16 (2 elems/thread, 16B stores) ----------------
__global__ __launch_bounds__(256) void bases_kernel(const float* __restrict__ x,
                                                    unsigned short* __restrict__ A) {
  int e0 = blockIdx.x * 512 + threadIdx.x * 2;
  float2 xv = *(const float2*)(x + e0);
  float w0[12], w1[12];
  spline12(xv.x, w0);
  spline12(xv.y, w1);
  unsigned short h[24];
  #pragma unroll
  for (int s = 0; s < 12; ++s) { h[s] = f2b(w0[s]); h[12 + s] = f2b(w1[s]); }
  u16x8* dst = (u16x8*)(A + (size_t)e0 * 12);   // 48B, 16B-aligned
  dst[0] = (u16x8){h[0],  h[1],  h[2],  h[3],  h[4],  h[5],  h[6],  h[7]};
  dst[1] = (u16x8){h[8],  h[9],  h[10], h[11], h[12], h[13], h[14], h[15]};
  dst[2] = (u16x8){h[16], h[17], h[18], h[19], h[20], h[21], h[22], h[23]};
}

// ---------------- Pass 1a: Bt[o][i*12+n] bf16 (coalesced transpose) ----------------
// grid (64, 16): block covers o-chunk of 16 (x), i-chunk of 64 (y).
__global__ __launch_bounds__(256) void repack_kernel(const float* __restrict__ coeffs,
                                                     const float* __restrict__ W,
                                                     unsigned short* __restrict__ Bt) {
  __shared__ float lc[64 * 176];   // [i][ol*11+n] f32 = 45 KB
  __shared__ float lw[64 * 16];    // [i][ol] f32 = 4 KB
  const int o0 = blockIdx.x * 16;
  const int i0 = blockIdx.y * 64;
  const int tid = threadIdx.x;
  #pragma unroll
  for (int it = 0; it < 11; ++it) {
    int v = it * 256 + tid;            // < 2816
    int i = v / 44, c = v - i * 44;
    f32x4 d = *(const f32x4*)(coeffs + ((size_t)(i0 + i) * 1024 + o0) * 11 + c * 4);
    *(f32x4*)(lc + i * 176 + c * 4) = d;
  }
  #pragma unroll
  for (int it = 0; it < 4; ++it) {
    int e = it * 256 + tid;            // < 1024
    int i = e >> 4, ol = e & 15;
    lw[e] = W[(size_t)(i0 + i) * 1024 + o0 + ol];
  }
  __syncthreads();
  #pragma unroll
  for (int it = 0; it < 6; ++it) {
    int v = it * 256 + tid;            // < 1536
    int ol = v / 96, c = v - ol * 96;
    unsigned short h[8];
    #pragma unroll
    for (int s = 0; s < 8; ++s) {
      int g = c * 8 + s;
      int i = g / 12, n = g - i * 12;
      float val = (n < 11) ? lc[i * 176 + ol * 11 + n] : lw[i * 16 + ol];
      h[s] = f2b(val);
    }
    *(u16x8*)(Bt + (size_t)(o0 + ol) * K_DIM + (size_t)i0 * 12 + c * 8) =
        (u16x8){h[0], h[1], h[2], h[3], h[4], h[5], h[6], h[7]};
  }
}

// ---------------- Pass 2: deep-pipelined split-K GEMM ----------------
// C[4096,1024] += A[4096,K]*Bt[1024,K]^T.  BM=256,BN=128,BK=64, 512 thr (8 waves 4m x 2n),
// 3-deep LDS tile ring, counted vmcnt(12), raw barriers.
__device__ __forceinline__ void async16(const void* g, void* l) {
  __builtin_amdgcn_global_load_lds(
      (const __attribute__((address_space(1))) void*)g,
      (__attribute__((address_space(3))) void*)l, 16, 0, 0);
}

__global__ __launch_bounds__(512, 1) void gemm_kernel(const unsigned short* __restrict__ A,
                                                      const unsigned short* __restrict__ Bt,
                                                      float* __restrict__ out) {
  // LDS: 3 A-slots [256][64] bf16 (32KB each) + 3 B-slots [128][64] (16KB each) = 144KB
  __shared__ __align__(16) unsigned short lds[73728];
  char* lp = (char*)lds;
  const int AS0 = 0, AS1 = 32768, AS2 = 65536;
  const int BS0 = 98304, BS1 = 98304 + 16384, BS2 = 98304 + 32768;

  const int tid  = threadIdx.x;
  const int lane = tid & 63;
  const int wid  = tid >> 6;          // 0..7
  const int wm   = wid >> 1;          // 0..3  (M)
  const int wn   = wid & 1;           // 0..1  (N)

  // block mapping: xcd = blk&7 -> bn (B-panel per XCD fits L2); r -> bm, ks
  const int blk = blockIdx.x;
  const int bn  = blk & 7;
  const int r   = blk >> 3;           // 0..31
  const int bm  = r & 15;
  const int ks  = r >> 4;             // 0..1
  const size_t m0 = (size_t)bm * 256;
  const size_t n0 = (size_t)bn * 128;
  const size_t ksbyte = (size_t)ks * KPART2 * 2;

  // per-thread staging addresses (chunk g = q*512 + tid; LDS linear dest,
  // source pre-swizzled: slot chunk cp holds logical chunk cp ^ (row&7))
  const char* srcA[4]; int ldsA[4];
  #pragma unroll
  for (int q = 0; q < 4; ++q) {
    int g = q * 512 + tid;            // 0..2047
    int rr = g >> 3, cp = g & 7;
    int cs = cp ^ (rr & 7);
    srcA[q] = (const char*)A + ((m0 + rr) * (size_t)K_DIM) * 2 + ksbyte + cs * 16;
    ldsA[q] = g * 16;
  }
  const char* srcB[2]; int ldsB[2];
  #pragma unroll
  for (int q = 0; q < 2; ++q) {
    int g = q * 512 + tid;            // 0..1023
    int rr = g >> 3, cp = g & 7;
    int cs = cp ^ (rr & 7);
    srcB[q] = (const char*)Bt + ((n0 + rr) * (size_t)K_DIM) * 2 + ksbyte + cs * 16;
    ldsB[q] = g * 16;
  }

  auto stage = [&](int sa, int sb, int tile) {
    size_t kb = (size_t)tile * 128;   // 64 bf16 per K-step
    #pragma unroll
    for (int q = 0; q < 4; ++q) async16(srcA[q] + kb, lp + sa + ldsA[q]);
    #pragma unroll
    for (int q = 0; q < 2; ++q) async16(srcB[q] + kb, lp + sb + ldsB[q]);
  };

  // ds_read byte offsets (xor-swizzled), constant over loop
  int offA[2][4], offB[2][4];
  #pragma unroll
  for (int kk = 0; kk < 2; ++kk) {
    #pragma unroll
    for (int m = 0; m < 4; ++m) {
      int row = wm * 64 + m * 16 + (lane & 15);
      int ck  = (kk * 4 + (lane >> 4)) ^ (row & 7);
      offA[kk][m] = row * 128 + ck * 16;
    }
    #pragma unroll
    for (int n = 0; n < 4; ++n) {
      int rowb = wn * 64 + n * 16 + (lane & 15);
      int ckb  = (kk * 4 + (lane >> 4)) ^ (rowb & 7);
      offB[kk][n] = rowb * 128 + ckb * 16;
    }
  }

  f32x4 acc[4][4];
  #pragma unroll
  for (int m = 0; m < 4; ++m)
    #pragma unroll
    for (int n = 0; n < 4; ++n) acc[m][n] = (f32x4){0.f, 0.f, 0.f, 0.f};

  // prologue: 3 tiles in flight (18 loads/thread)
  stage(AS0, BS0, 0);
  stage(AS1, BS1, 1);
  stage(AS2, BS2, 2);

  int cA = AS0, nA = AS1, fA = AS2;
  int cB = BS0, nB = BS1, fB = BS2;

  for (int t = 0; t < NT; ++t) {
    // gate: tile t landed; tiles t+1, t+2 (12 loads) stay in flight
    if (t < NT - 2)       asm volatile("s_waitcnt vmcnt(12)" ::: "memory");
    else if (t == NT - 2) asm volatile("s_waitcnt vmcnt(6)"  ::: "memory");
    else                  asm volatile("s_waitcnt vmcnt(0)"  ::: "memory");
    __builtin_amdgcn_s_barrier();
    __builtin_amdgcn_sched_barrier(0);
    asm volatile("" ::: "memory");

    __builtin_amdgcn_s_setprio(1);
    #pragma unroll
    for (int kk = 0; kk < 2; ++kk) {
      bf16x8 a[4], b[4];
      #pragma unroll
      for (int m = 0; m < 4; ++m) a[m] = *(const bf16x8*)(lp + cA + offA[kk][m]);
      #pragma unroll
      for (int n = 0; n < 4; ++n) b[n] = *(const bf16x8*)(lp + cB + offB[kk][n]);
      #pragma unroll
      for (int m = 0; m < 4; ++m)
        #pragma unroll
        for (int n = 0; n < 4; ++n)
          acc[m][n] = __builtin_amdgcn_mfma_f32_16x16x32_bf16(a[m], b[n], acc[m][n], 0, 0, 0);
    }
    __builtin_amdgcn_s_setprio(0);

    asm volatile("" ::: "memory");
    __builtin_amdgcn_sched_barrier(0);
    __builtin_amdgcn_s_barrier();       // all waves done reading cur slot

    if (t + 3 < NT) stage(cA, cB, t + 3);   // restage freed slot

    int ta = cA; cA = nA; nA = fA; fA = ta;
    int tb = cB; cB = nB; nB = fB; fB = tb;
  }

  const int lr = (lane >> 4) * 4;   // C/D: col=lane&15, row=(lane>>4)*4+j
  const int lc = lane & 15;
  #pragma unroll
  for (int m = 0; m < 4; ++m)
    #pragma unroll
    for (int n = 0; n < 4; ++n)
      #pragma unroll
      for (int j = 0; j < 4; ++j)
        atomicAdd(&out[(m0 + wm * 64 + m * 16 + lr + j) * N_DIM + n0 + wn * 64 + n * 16 + lc],
                  acc[m][n][j]);
}

// ---------------- Fallback (correctness insurance if ws too small) ----------------
__global__ __launch_bounds__(256) void fallback_kernel(const float* __restrict__ x,
                                                       const float* __restrict__ coeffs,
                                                       const float* __restrict__ W,
                                                       float* __restrict__ out) {
  __shared__ float bas[16][64][12];
  const int o0 = blockIdx.x * 64;
  const int b0 = blockIdx.y * 16;
  const int tid = threadIdx.x;
  const int o = tid & 63, bg = tid >> 6;
  float acc[4] = {0.f, 0.f, 0.f, 0.f};
  for (int ic = 0; ic < 16; ++ic) {
    __syncthreads();
    #pragma unroll
    for (int p = 0; p < 4; ++p) {
      int pp = tid + p * 256;
      int bb = pp >> 6, il = pp & 63;
      float w[12];
      spline12(x[(size_t)(b0 + bb) * 1024 + ic * 64 + il], w);
      #pragma unroll
      for (int n = 0; n < 12; ++n) bas[bb][il][n] = w[n];
    }
    __syncthreads();
    for (int il = 0; il < 64; ++il) {
      int gi = ic * 64 + il;
      const float* cp = coeffs + ((size_t)gi * 1024 + o0 + o) * 11;
      float cf[12];
      #pragma unroll
      for (int n = 0; n < 11; ++n) cf[n] = cp[n];
      cf[11] = W[(size_t)gi * 1024 + o0 + o];
      #pragma unroll
      for (int bb = 0; bb < 4; ++bb) {
        float s = 0.f;
        #pragma unroll
        for (int n = 0; n < 12; ++n) s += bas[bg * 4 + bb][il][n] * cf[n];
        acc[bb] += s;
      }
    }
  }
  #pragma unroll
  for (int bb = 0; bb < 4; ++bb)
    out[(size_t)(b0 + bg * 4 + bb) * 1024 + o0 + o] = acc[bb];
}

extern "C" void kernel_launch(void* const* d_in, const int* in_sizes, int n_in,
                              void* d_out, int out_size, void* d_ws, size_t ws_size,
                              hipStream_t stream) {
  const float* x      = (const float*)d_in[0];   // [4096,1024]
  const float* coeffs = (const float*)d_in[1];   // [1024,1024,11]
  const float* W      = (const float*)d_in[2];   // [1024,1024]
  float* out = (float*)d_out;

  const size_t needA = (size_t)M_DIM * K_DIM * 2;
  const size_t needB = (size_t)N_DIM * K_DIM * 2;

  if (ws_size >= needA + needB) {
    unsigned short* Abuf = (unsigned short*)d_ws;
    unsigned short* Btuf = (unsigned short*)((char*)d_ws + needA);
    hipMemsetAsync(out, 0, (size_t)out_size * sizeof(float), stream);
    bases_kernel<<<dim3(M_DIM * IN_F / 512), dim3(256), 0, stream>>>(x, Abuf);
    repack_kernel<<<dim3(64, 16), dim3(256), 0, stream>>>(coeffs, W, Btuf);
    gemm_kernel<<<dim3(16 * 8 * KS2), dim3(512), 0, stream>>>(Abuf, Btuf, out);
  } else {
    fallback_kernel<<<dim3(16, 256), dim3(256), 0, stream>>>(x, coeffs, W, out);
  }
}

// Round 5
// 236.901 us; speedup vs baseline: 1.1679x; 1.1679x over previous
//
#include <hip/hip_runtime.h>
#include <hip/hip_bf16.h>

typedef __attribute__((ext_vector_type(8))) short bf16x8;
typedef __attribute__((ext_vector_type(4))) float f32x4;
typedef __attribute__((ext_vector_type(8))) unsigned short u16x8;

#define M_DIM 4096
#define N_DIM 1024
#define IN_F  1024
#define K_DIM 12288   // IN_F * 12  (11 spline slots + 1 residual slot)
#define KS2   2
#define KPART (K_DIM / KS2)    // 6144
#define BK 64
#define NT (KPART / BK)        // 96

__device__ __forceinline__ unsigned short f2b(float v) {
  __hip_bfloat16 h = __float2bfloat16(v);
  return *reinterpret_cast<unsigned short*>(&h);
}

// Uniform cubic B-spline, grid = linspace(-1.75, 1.75, 15), h = 0.25.
__device__ __forceinline__ void spline12(float xv, float* w) {
  float t  = tanhf(xv);
  float tf = (t + 1.75f) * 4.0f;          // in (3,11) since t in (-1,1)
  int j = (int)tf;
  j = j < 3 ? 3 : (j > 10 ? 10 : j);
  float u  = tf - (float)j;
  float um = 1.0f - u;
  float u2 = u * u;
  float w0 = um * um * um * (1.0f / 6.0f);
  float w1 = (0.5f * u - 1.0f) * u2 + (2.0f / 3.0f);
  float w2 = ((-0.5f * u + 0.5f) * u + 0.5f) * u + (1.0f / 6.0f);
  float w3 = u * u2 * (1.0f / 6.0f);
  int base = j - 3;                        // in [0,7]
  #pragma unroll
  for (int s = 0; s < 11; ++s) {
    int r = s - base;
    w[s] = (r == 0) ? w0 : (r == 1) ? w1 : (r == 2) ? w2 : (r == 3) ? w3 : 0.0f;
  }
  w[11] = xv;
}

// ---------------- Pass 1b: A[b][i*12+n] bf16, LDS-transposed coalesced stores ----------------
__global__ __launch_bounds__(256) void bases_kernel(const float* __restrict__ x,
                                                    unsigned short* __restrict__ A) {
  __shared__ unsigned short sb[256 * 24];   // 12 KB
  const int tid = threadIdx.x;
  int e0 = blockIdx.x * 512 + tid * 2;
  float2 xv = *(const float2*)(x + e0);
  float w0[12], w1[12];
  spline12(xv.x, w0);
  spline12(xv.y, w1);
  #pragma unroll
  for (int s = 0; s < 12; ++s) { sb[tid * 24 + s] = f2b(w0[s]); sb[tid * 24 + 12 + s] = f2b(w1[s]); }
  __syncthreads();
  u16x8* dst = (u16x8*)(A + (size_t)blockIdx.x * 512 * 12);
  const u16x8* src = (const u16x8*)sb;
  #pragma unroll
  for (int k = 0; k < 3; ++k) dst[tid + k * 256] = src[tid + k * 256];
}

// ---------------- Pass 1a: Bt[o][i*12+n] bf16 (coalesced transpose, padded LDS) ----------------
// grid (64, 16): block covers o-chunk of 16 (x), i-chunk of 64 (y).
__global__ __launch_bounds__(256) void repack_kernel(const float* __restrict__ coeffs,
                                                     const float* __restrict__ W,
                                                     unsigned short* __restrict__ Bt) {
  __shared__ float lc[64 * 180];   // [i][ol*11+n], stride 180 (16B-aligned, conflict-reduced)
  __shared__ float lw[64 * 20];    // [i][ol], stride 20
  const int o0 = blockIdx.x * 16;
  const int i0 = blockIdx.y * 64;
  const int tid = threadIdx.x;
  #pragma unroll
  for (int it = 0; it < 11; ++it) {
    int v = it * 256 + tid;            // < 2816
    int i = v / 44, c = v - i * 44;
    f32x4 d = *(const f32x4*)(coeffs + ((size_t)(i0 + i) * 1024 + o0) * 11 + c * 4);
    *(f32x4*)(lc + i * 180 + c * 4) = d;
  }
  #pragma unroll
  for (int it = 0; it < 4; ++it) {
    int e = it * 256 + tid;            // < 1024
    int i = e >> 4, ol = e & 15;
    lw[i * 20 + ol] = W[(size_t)(i0 + i) * 1024 + o0 + ol];
  }
  __syncthreads();
  #pragma unroll
  for (int it = 0; it < 6; ++it) {
    int v = it * 256 + tid;            // < 1536
    int ol = v / 96, c = v - ol * 96;
    unsigned short h[8];
    #pragma unroll
    for (int s = 0; s < 8; ++s) {
      int g = c * 8 + s;
      int i = g / 12, n = g - i * 12;
      float val = (n < 11) ? lc[i * 180 + ol * 11 + n] : lw[i * 20 + ol];
      h[s] = f2b(val);
    }
    *(u16x8*)(Bt + (size_t)(o0 + ol) * K_DIM + (size_t)i0 * 12 + c * 8) =
        (u16x8){h[0], h[1], h[2], h[3], h[4], h[5], h[6], h[7]};
  }
}

// ---------------- Pass 2: split-K GEMM, 2-slot ring, counted vmcnt ----------------
// C[4096,1024] += A[4096,K]*Bt[1024,K]^T.  BM=BN=128, BK=64, 256 thr (4 waves 2x2),
// 2 blocks/CU, A-panel exclusive per XCD.
__device__ __forceinline__ void async16(const void* g, void* l) {
  __builtin_amdgcn_global_load_lds(
      (const __attribute__((address_space(1))) void*)g,
      (__attribute__((address_space(3))) void*)l, 16, 0, 0);
}

__global__ __launch_bounds__(256, 2) void gemm_kernel(const unsigned short* __restrict__ A,
                                                      const unsigned short* __restrict__ Bt,
                                                      float* __restrict__ out) {
  // 2 slots x (A 16KB + B 16KB) = 64 KB
  __shared__ __align__(16) unsigned short lds[32768];
  char* lp = (char*)lds;
  const int AS[2] = {0, 16384};
  const int BS[2] = {32768, 49152};

  const int tid  = threadIdx.x;
  const int lane = tid & 63;
  const int wid  = tid >> 6;          // 0..3
  const int wm   = wid >> 1, wn = wid & 1;

  // A-exclusive XCD map: xcd = blk&7 owns bm in [xcd*4, xcd*4+4) for each ks.
  const int blk = blockIdx.x;          // 0..511
  const int xcd = blk & 7;
  const int idx = blk >> 3;            // 0..63
  const int bn  = idx & 7;
  const int p   = idx >> 3;            // 0..7 : panel id within XCD
  const int bm  = xcd * 4 + (p & 3);   // 0..31
  const int ks  = p >> 2;              // 0..1
  const size_t m0 = (size_t)bm * 128;
  const size_t n0 = (size_t)bn * 128;
  const size_t ksbyte = (size_t)ks * KPART * 2;

  // staging: tile = [128 rows][64 k] bf16 = 1024 x 16B chunks; 4 chunks/thread/matrix.
  // LDS linear dest; global source pre-swizzled (rule #21): slot chunk cp holds cp^(row&7).
  const char* srcA[4]; const char* srcB[4]; int ldso[4];
  #pragma unroll
  for (int q = 0; q < 4; ++q) {
    int g  = q * 256 + tid;            // 0..1023
    int rr = g >> 3, cp = g & 7;
    int cs = cp ^ (rr & 7);
    srcA[q] = (const char*)A  + ((m0 + rr) * (size_t)K_DIM) * 2 + ksbyte + cs * 16;
    srcB[q] = (const char*)Bt + ((n0 + rr) * (size_t)K_DIM) * 2 + ksbyte + cs * 16;
    ldso[q] = g * 16;
  }

  auto stage = [&](int slot, int tile) {
    size_t kb = (size_t)tile * 128;    // 64 bf16 = 128 B per K-step
    #pragma unroll
    for (int q = 0; q < 4; ++q) async16(srcA[q] + kb, lp + AS[slot] + ldso[q]);
    #pragma unroll
    for (int q = 0; q < 4; ++q) async16(srcB[q] + kb, lp + BS[slot] + ldso[q]);
  };

  // ds_read byte offsets (xor-swizzled), constant over loop
  int offA[2][4], offB[2][4];
  #pragma unroll
  for (int kk = 0; kk < 2; ++kk) {
    #pragma unroll
    for (int m = 0; m < 4; ++m) {
      int row = wm * 64 + m * 16 + (lane & 15);
      int ck  = (kk * 4 + (lane >> 4)) ^ (row & 7);
      offA[kk][m] = row * 128 + ck * 16;
      int rowb = wn * 64 + m * 16 + (lane & 15);
      int ckb  = (kk * 4 + (lane >> 4)) ^ (rowb & 7);
      offB[kk][m] = rowb * 128 + ckb * 16;
    }
  }

  f32x4 acc[4][4];
  #pragma unroll
  for (int m = 0; m < 4; ++m)
    #pragma unroll
    for (int n = 0; n < 4; ++n) acc[m][n] = (f32x4){0.f, 0.f, 0.f, 0.f};

  stage(0, 0);
  stage(1, 1);

  for (int t = 0; t < NT; ++t) {
    const int cur = t & 1;
    // gate: tile t landed; tile t+1's 8 loads stay in flight across both barriers
    if (t < NT - 1) asm volatile("s_waitcnt vmcnt(8)" ::: "memory");
    else            asm volatile("s_waitcnt vmcnt(0)" ::: "memory");
    __builtin_amdgcn_s_barrier();
    __builtin_amdgcn_sched_barrier(0);
    asm volatile("" ::: "memory");

    __builtin_amdgcn_s_setprio(1);
    #pragma unroll
    for (int kk = 0; kk < 2; ++kk) {
      bf16x8 a[4], b[4];
      #pragma unroll
      for (int m = 0; m < 4; ++m) a[m] = *(const bf16x8*)(lp + AS[cur] + offA[kk][m]);
      #pragma unroll
      for (int n = 0; n < 4; ++n) b[n] = *(const bf16x8*)(lp + BS[cur] + offB[kk][n]);
      #pragma unroll
      for (int m = 0; m < 4; ++m)
        #pragma unroll
        for (int n = 0; n < 4; ++n)
          acc[m][n] = __builtin_amdgcn_mfma_f32_16x16x32_bf16(a[m], b[n], acc[m][n], 0, 0, 0);
    }
    __builtin_amdgcn_s_setprio(0);

    asm volatile("" ::: "memory");
    __builtin_amdgcn_sched_barrier(0);
    __builtin_amdgcn_s_barrier();       // all waves done reading slot cur

    if (t + 2 < NT) stage(cur, t + 2);
  }

  const int lr = (lane >> 4) * 4;   // C/D: col=lane&15, row=(lane>>4)*4+j
  const int lc = lane & 15;
  #pragma unroll
  for (int m = 0; m < 4; ++m)
    #pragma unroll
    for (int n = 0; n < 4; ++n)
      #pragma unroll
      for (int j = 0; j < 4; ++j)
        atomicAdd(&out[(m0 + wm * 64 + m * 16 + lr + j) * N_DIM + n0 + wn * 64 + n * 16 + lc],
                  acc[m][n][j]);
}

// ---------------- Fallback (correctness insurance if ws too small) ----------------
__global__ __launch_bounds__(256) void fallback_kernel(const float* __restrict__ x,
                                                       const float* __restrict__ coeffs,
                                                       const float* __restrict__ W,
                                                       float* __restrict__ out) {
  __shared__ float bas[16][64][12];
  const int o0 = blockIdx.x * 64;
  const int b0 = blockIdx.y * 16;
  const int tid = threadIdx.x;
  const int o = tid & 63, bg = tid >> 6;
  float acc[4] = {0.f, 0.f, 0.f, 0.f};
  for (int ic = 0; ic < 16; ++ic) {
    __syncthreads();
    #pragma unroll
    for (int p = 0; p < 4; ++p) {
      int pp = tid + p * 256;
      int bb = pp >> 6, il = pp & 63;
      float w[12];
      spline12(x[(size_t)(b0 + bb) * 1024 + ic * 64 + il], w);
      #pragma unroll
      for (int n = 0; n < 12; ++n) bas[bb][il][n] = w[n];
    }
    __syncthreads();
    for (int il = 0; il < 64; ++il) {
      int gi = ic * 64 + il;
      const float* cp = coeffs + ((size_t)gi * 1024 + o0 + o) * 11;
      float cf[12];
      #pragma unroll
      for (int n = 0; n < 11; ++n) cf[n] = cp[n];
      cf[11] = W[(size_t)gi * 1024 + o0 + o];
      #pragma unroll
      for (int bb = 0; bb < 4; ++bb) {
        float s = 0.f;
        #pragma unroll
        for (int n = 0; n < 12; ++n) s += bas[bg * 4 + bb][il][n] * cf[n];
        acc[bb] += s;
      }
    }
  }
  #pragma unroll
  for (int bb = 0; bb < 4; ++bb)
    out[(size_t)(b0 + bg * 4 + bb) * 1024 + o0 + o] = acc[bb];
}

extern "C" void kernel_launch(void* const* d_in, const int* in_sizes, int n_in,
                              void* d_out, int out_size, void* d_ws, size_t ws_size,
                              hipStream_t stream) {
  const float* x      = (const float*)d_in[0];   // [4096,1024]
  const float* coeffs = (const float*)d_in[1];   // [1024,1024,11]
  const float* W      = (const float*)d_in[2];   // [1024,1024]
  float* out = (float*)d_out;

  const size_t needA = (size_t)M_DIM * K_DIM * 2;
  const size_t needB = (size_t)N_DIM * K_DIM * 2;

  if (ws_size >= needA + needB) {
    unsigned short* Abuf = (unsigned short*)d_ws;
    unsigned short* Btuf = (unsigned short*)((char*)d_ws + needA);
    hipMemsetAsync(out, 0, (size_t)out_size * sizeof(float), stream);
    bases_kernel<<<dim3(M_DIM * IN_F / 512), dim3(256), 0, stream>>>(x, Abuf);
    repack_kernel<<<dim3(64, 16), dim3(256), 0, stream>>>(coeffs, W, Btuf);
    gemm_kernel<<<dim3(32 * 8 * KS2 / 2 * 2), dim3(256), 0, stream>>>(Abuf, Btuf, out);
  } else {
    fallback_kernel<<<dim3(16, 256), dim3(256), 0, stream>>>(x, coeffs, W, out);
  }
}